// Round 4
// baseline (146.623 us; speedup 1.0000x reference)
//
#include <hip/hip_runtime.h>
#include <hip/hip_bf16.h>
#include <math.h>

#define T_TOK   32768
#define HIDDEN  2048
#define NEXP    8
#define ROWF4   (HIDDEN / 4)      // 512 float4 per token row
#define NSLICE  8                 // K-split factor
#define HS_F4   (ROWF4 / NSLICE)  // 64 float4 (256 f32) per slice
#define CHUNK   8                 // float4 per chunk (32 f32)
#define NCHUNK  (HS_F4 / CHUNK)   // 8 chunks per slice
#define TPB     256               // tokens per router block (1 per thread)
#define BLOCK   256
#define PITCH   9                 // float4 pitch in LDS (pad: 8-cyc balanced banks)
#define RGRID   ((T_TOK / TPB) * NSLICE)   // 1024 blocks

#define SCORES_OFF 0
#define IDX_OFF    (T_TOK * 2)    // 65536
#define HIST_OFF   (T_TOK * 4)    // 131072

__device__ __forceinline__ float4 f4mul(float4 a, float4 b) {
    float4 r; r.x = a.x * b.x; r.y = a.y * b.y; r.z = a.z * b.z; r.w = a.w * b.w;
    return r;
}
__device__ __forceinline__ float4 f4fma(float4 a, float4 b, float4 c) {
    float4 r;
    r.x = fmaf(a.x, b.x, c.x); r.y = fmaf(a.y, b.y, c.y);
    r.z = fmaf(a.z, b.z, c.z); r.w = fmaf(a.w, b.w, c.w);
    return r;
}

// router: each thread owns one token, computes partial logits over its
// 256-wide hidden slice. x staged via LDS tile (transpose to per-lane rows);
// W read with block-uniform addresses -> s_load broadcast (no LDS for W).
__global__ __launch_bounds__(BLOCK) void router_kernel(
        const float4* __restrict__ x4, const float4* __restrict__ W4,
        float* __restrict__ out, float* __restrict__ partial /*[NSLICE][T][E]*/) {
    __shared__ float4 xt[TPB * PITCH];          // 36 KB

    const int tid   = threadIdx.x;
    const int slice = blockIdx.x & (NSLICE - 1);
    const int tg    = blockIdx.x >> 3;
    const int t0    = tg * TPB;
    const int hbase = slice * HS_F4;            // float4 index into a row

    if (blockIdx.x == 0 && tid < NEXP) out[HIST_OFF + tid] = 0.0f;  // runs before combine (stream order)

    // stage chunk 0
    float4 rg[CHUNK];
#pragma unroll
    for (int r = 0; r < CHUNK; ++r) {
        const int idx = r * TPB + tid, tok = idx >> 3, j = idx & 7;
        rg[r] = x4[(size_t)(t0 + tok) * ROWF4 + hbase + j];
    }
#pragma unroll
    for (int r = 0; r < CHUNK; ++r) {
        const int idx = r * TPB + tid, tok = idx >> 3, j = idx & 7;
        xt[tok * PITCH + j] = rg[r];
    }
    __syncthreads();

    double acc[NEXP];
#pragma unroll
    for (int e = 0; e < NEXP; ++e) acc[e] = 0.0;

#pragma unroll 1
    for (int c = 0; c < NCHUNK; ++c) {
        // T14: issue next chunk's loads early; latency hides under compute
        if (c + 1 < NCHUNK) {
#pragma unroll
            for (int r = 0; r < CHUNK; ++r) {
                const int idx = r * TPB + tid, tok = idx >> 3, j = idx & 7;
                rg[r] = x4[(size_t)(t0 + tok) * ROWF4 + hbase + (c + 1) * CHUNK + j];
            }
        }
        // my token's chunk from LDS (pitch 9 -> conflict-free b128)
        float4 rv[CHUNK];
#pragma unroll
        for (int j = 0; j < CHUNK; ++j) rv[j] = xt[tid * PITCH + j];

#pragma unroll
        for (int e = 0; e < NEXP; ++e) {
            const float4* wp = &W4[(size_t)e * ROWF4 + hbase + c * CHUNK];  // uniform -> s_load
#pragma unroll
            for (int g = 0; g < 2; ++g) {
                const float4 w0 = wp[4 * g + 0], w1 = wp[4 * g + 1];
                const float4 w2 = wp[4 * g + 2], w3 = wp[4 * g + 3];
                float4 sv = f4mul(rv[4 * g + 0], w0);
                sv = f4fma(rv[4 * g + 1], w1, sv);
                sv = f4fma(rv[4 * g + 2], w2, sv);
                sv = f4fma(rv[4 * g + 3], w3, sv);
                // 16-element group -> one f64 accumulate
                acc[e] += (double)((sv.x + sv.y) + (sv.z + sv.w));
            }
        }
        __syncthreads();            // everyone done reading xt
        if (c + 1 < NCHUNK) {
#pragma unroll
            for (int r = 0; r < CHUNK; ++r) {
                const int idx = r * TPB + tid, tok = idx >> 3, j = idx & 7;
                xt[tok * PITCH + j] = rg[r];
            }
            __syncthreads();        // xt holds chunk c+1
        }
    }

    // f32 partials: [slice][token][expert], 32-B aligned -> two float4 stores
    float4 p0, p1;
    p0.x = (float)acc[0]; p0.y = (float)acc[1]; p0.z = (float)acc[2]; p0.w = (float)acc[3];
    p1.x = (float)acc[4]; p1.y = (float)acc[5]; p1.z = (float)acc[6]; p1.w = (float)acc[7];
    float4* pp = reinterpret_cast<float4*>(&partial[((size_t)slice * T_TOK + (t0 + tid)) * NEXP]);
    pp[0] = p0; pp[1] = p1;
}

__global__ __launch_bounds__(256) void combine_kernel(
        const float* __restrict__ partial, float* __restrict__ out) {
    __shared__ float h[NEXP];
    const int tid = threadIdx.x;
    const int t   = blockIdx.x * 256 + tid;
    if (tid < NEXP) h[tid] = 0.0f;
    __syncthreads();

    double lg[NEXP];
#pragma unroll
    for (int e = 0; e < NEXP; ++e) lg[e] = 0.0;
#pragma unroll
    for (int s = 0; s < NSLICE; ++s) {
        const float4* pp = reinterpret_cast<const float4*>(
            &partial[((size_t)s * T_TOK + t) * NEXP]);
        const float4 a = pp[0], b = pp[1];
        lg[0] += (double)a.x; lg[1] += (double)a.y; lg[2] += (double)a.z; lg[3] += (double)a.w;
        lg[4] += (double)b.x; lg[5] += (double)b.y; lg[6] += (double)b.z; lg[7] += (double)b.w;
    }

    // top-2, lowest-index tie-break (strict >), matching jax.lax.top_k
    double b1 = lg[0]; int i1 = 0;
    double b2 = -1.0e300; int i2 = 0;
#pragma unroll
    for (int e = 1; e < NEXP; ++e) {
        const double v = lg[e];
        if (v > b1)      { b2 = b1; i2 = i1; b1 = v; i1 = e; }
        else if (v > b2) { b2 = v;  i2 = e; }
    }
    const float d  = (float)(b2 - b1);
    const float e1 = expf(d);
    const float s0 = 1.0f / (1.0f + e1);

    float2 sc; sc.x = s0; sc.y = e1 * s0;
    float2 ix; ix.x = (float)i1; ix.y = (float)i2;
    *reinterpret_cast<float2*>(out + SCORES_OFF + 2 * t) = sc;
    *reinterpret_cast<float2*>(out + IDX_OFF    + 2 * t) = ix;

    atomicAdd(&h[i1], 1.0f);
    atomicAdd(&h[i2], 1.0f);
    __syncthreads();
    if (tid < NEXP) atomicAdd(&out[HIST_OFF + tid], h[tid]);
}

extern "C" void kernel_launch(void* const* d_in, const int* in_sizes, int n_in,
                              void* d_out, int out_size, void* d_ws, size_t ws_size,
                              hipStream_t stream) {
    const float4* x4 = (const float4*)d_in[0];
    const float4* W4 = (const float4*)d_in[1];
    float* out       = (float*)d_out;
    float* partial   = (float*)d_ws;   // 8 MB of the 1 GB workspace

    router_kernel<<<RGRID, BLOCK, 0, stream>>>(x4, W4, out, partial);
    combine_kernel<<<T_TOK / 256, 256, 0, stream>>>(partial, out);
}

// Round 5
// 134.114 us; speedup vs baseline: 1.0933x; 1.0933x over previous
//
#include <hip/hip_runtime.h>
#include <hip/hip_bf16.h>
#include <math.h>

#define T_TOK   32768
#define HIDDEN  2048
#define NEXP    8
#define ROWF4   (HIDDEN / 4)      // 512 float4 per token row
#define NSLICE  8                 // K-split factor
#define HS_F4   (ROWF4 / NSLICE)  // 64 float4 (256 f32) per slice
#define CHUNK   4                 // float4 per chunk per token (16 f32)
#define NCHUNK  (HS_F4 / CHUNK)   // 16 chunks per slice
#define TPB     256               // tokens per router block (1 per thread)
#define BLOCK   256
#define PITCH   5                 // float4 pitch in LDS (odd-ish: conflict-free b128 reads)
#define RGRID   ((T_TOK / TPB) * NSLICE)   // 1024 blocks = 4/CU

#define SCORES_OFF 0
#define IDX_OFF    (T_TOK * 2)    // 65536
#define HIST_OFF   (T_TOK * 4)    // 131072

__device__ __forceinline__ float4 f4mul(float4 a, float4 b) {
    float4 r; r.x = a.x * b.x; r.y = a.y * b.y; r.z = a.z * b.z; r.w = a.w * b.w;
    return r;
}
__device__ __forceinline__ float4 f4fma(float4 a, float4 b, float4 c) {
    float4 r;
    r.x = fmaf(a.x, b.x, c.x); r.y = fmaf(a.y, b.y, c.y);
    r.z = fmaf(a.z, b.z, c.z); r.w = fmaf(a.w, b.w, c.w);
    return r;
}

// Each thread owns one token; lanes-split-tokens, W read at block-uniform
// addresses -> s_load scalar broadcast (no W in LDS, no shuffles).
// x staged through a double-buffered LDS transpose tile, one barrier/chunk.
// __launch_bounds__(256,4): cap VGPR at 128 (live ~80) -- round-4's plain
// bounds let regalloc pick 72 and spill 231 MB of scratch.
__global__ __launch_bounds__(BLOCK, 4) void router_kernel(
        const float4* __restrict__ x4, const float4* __restrict__ W4,
        float* __restrict__ out, float* __restrict__ partial /*[NSLICE][T][E]*/) {
    __shared__ float4 xt[2][TPB * PITCH];       // 2 x 20 KB

    const int tid   = threadIdx.x;
    const int slice = blockIdx.x & (NSLICE - 1);
    const int tg    = blockIdx.x >> 3;
    const int t0    = tg * TPB;
    const int hbase = slice * HS_F4;            // float4 index into a row

    if (blockIdx.x == 0 && tid < NEXP) out[HIST_OFF + tid] = 0.0f;  // precedes combine (stream order)

    const int stok = (tid >> 2);                // token this thread stages (base)
    const int sj   = (tid & 3);                 // float4 within chunk

    // stage chunk 0 into buf 0
    float4 rg[CHUNK];
#pragma unroll
    for (int r = 0; r < CHUNK; ++r)
        rg[r] = x4[(size_t)(t0 + stok + r * (TPB / CHUNK)) * ROWF4 + hbase + sj];
#pragma unroll
    for (int r = 0; r < CHUNK; ++r)
        xt[0][(stok + r * (TPB / CHUNK)) * PITCH + sj] = rg[r];
    __syncthreads();

    double acc[NEXP];
#pragma unroll
    for (int e = 0; e < NEXP; ++e) acc[e] = 0.0;

#pragma unroll 1
    for (int c = 0; c < NCHUNK; ++c) {
        // T14: issue next chunk's global loads early; hide under FMA phase
        if (c + 1 < NCHUNK) {
#pragma unroll
            for (int r = 0; r < CHUNK; ++r)
                rg[r] = x4[(size_t)(t0 + stok + r * (TPB / CHUNK)) * ROWF4
                           + hbase + (c + 1) * CHUNK + sj];
        }
        // my token's chunk from LDS (pitch 5 -> conflict-free b128)
        float4 rv[CHUNK];
#pragma unroll
        for (int j = 0; j < CHUNK; ++j) rv[j] = xt[c & 1][tid * PITCH + j];

#pragma unroll
        for (int e = 0; e < NEXP; ++e) {
            const float4* wp = &W4[(size_t)e * ROWF4 + hbase + c * CHUNK];  // uniform -> s_load
            float4 sv = f4mul(rv[0], wp[0]);
            sv = f4fma(rv[1], wp[1], sv);
            sv = f4fma(rv[2], wp[2], sv);
            sv = f4fma(rv[3], wp[3], sv);
            // one f64 accumulate per 16 elements (same error class as r2-r4, all passed)
            acc[e] += (double)((sv.x + sv.y) + (sv.z + sv.w));
        }

        // write next chunk into the other buffer; single barrier per chunk.
        // (buf[(c+1)&1] was last READ at chunk c-1, before that chunk's barrier)
        if (c + 1 < NCHUNK) {
#pragma unroll
            for (int r = 0; r < CHUNK; ++r)
                xt[(c + 1) & 1][(stok + r * (TPB / CHUNK)) * PITCH + sj] = rg[r];
        }
        __syncthreads();
    }

    // f32 partials: [slice][token][expert], 32-B aligned -> two float4 stores
    float4 p0, p1;
    p0.x = (float)acc[0]; p0.y = (float)acc[1]; p0.z = (float)acc[2]; p0.w = (float)acc[3];
    p1.x = (float)acc[4]; p1.y = (float)acc[5]; p1.z = (float)acc[6]; p1.w = (float)acc[7];
    float4* pp = reinterpret_cast<float4*>(&partial[((size_t)slice * T_TOK + (t0 + tid)) * NEXP]);
    pp[0] = p0; pp[1] = p1;
}

__global__ __launch_bounds__(256) void combine_kernel(
        const float* __restrict__ partial, float* __restrict__ out) {
    __shared__ float h[NEXP];
    const int tid = threadIdx.x;
    const int t   = blockIdx.x * 256 + tid;
    if (tid < NEXP) h[tid] = 0.0f;
    __syncthreads();

    double lg[NEXP];
#pragma unroll
    for (int e = 0; e < NEXP; ++e) lg[e] = 0.0;
#pragma unroll
    for (int s = 0; s < NSLICE; ++s) {
        const float4* pp = reinterpret_cast<const float4*>(
            &partial[((size_t)s * T_TOK + t) * NEXP]);
        const float4 a = pp[0], b = pp[1];
        lg[0] += (double)a.x; lg[1] += (double)a.y; lg[2] += (double)a.z; lg[3] += (double)a.w;
        lg[4] += (double)b.x; lg[5] += (double)b.y; lg[6] += (double)b.z; lg[7] += (double)b.w;
    }

    // top-2, lowest-index tie-break (strict >), matching jax.lax.top_k
    double b1 = lg[0]; int i1 = 0;
    double b2 = -1.0e300; int i2 = 0;
#pragma unroll
    for (int e = 1; e < NEXP; ++e) {
        const double v = lg[e];
        if (v > b1)      { b2 = b1; i2 = i1; b1 = v; i1 = e; }
        else if (v > b2) { b2 = v;  i2 = e; }
    }
    const float d  = (float)(b2 - b1);
    const float e1 = expf(d);
    const float s0 = 1.0f / (1.0f + e1);

    float2 sc; sc.x = s0; sc.y = e1 * s0;
    float2 ix; ix.x = (float)i1; ix.y = (float)i2;
    *reinterpret_cast<float2*>(out + SCORES_OFF + 2 * t) = sc;
    *reinterpret_cast<float2*>(out + IDX_OFF    + 2 * t) = ix;

    atomicAdd(&h[i1], 1.0f);
    atomicAdd(&h[i2], 1.0f);
    __syncthreads();
    if (tid < NEXP) atomicAdd(&out[HIST_OFF + tid], h[tid]);
}

extern "C" void kernel_launch(void* const* d_in, const int* in_sizes, int n_in,
                              void* d_out, int out_size, void* d_ws, size_t ws_size,
                              hipStream_t stream) {
    const float4* x4 = (const float4*)d_in[0];
    const float4* W4 = (const float4*)d_in[1];
    float* out       = (float*)d_out;
    float* partial   = (float*)d_ws;   // 8 MB of the 1 GB workspace

    router_kernel<<<RGRID, BLOCK, 0, stream>>>(x4, W4, out, partial);
    combine_kernel<<<T_TOK / 256, 256, 0, stream>>>(partial, out);
}